// Round 4
// baseline (1206.947 us; speedup 1.0000x reference)
//
#include <hip/hip_runtime.h>
#include <hip/hip_bf16.h>
#include <math.h>

typedef __attribute__((ext_vector_type(8))) short s16x8;
typedef __attribute__((ext_vector_type(4))) float f32x4;

static __device__ __forceinline__ float b2f(unsigned short u) {
    union { unsigned int u; float f; } x; x.u = ((unsigned int)u) << 16; return x.f;
}
static __device__ __forceinline__ unsigned short f2b(float f) {
    __hip_bfloat16 h = __float2bfloat16(f);
    return *reinterpret_cast<unsigned short*>(&h);
}
// tanh-approx GELU in sigmoid form: x * sigmoid(1.5957691*x*(1+0.044715*x^2)).
// ~7 VALU insts (1 v_exp, 1 v_rcp) vs ~60 for libm erff.
static __device__ __forceinline__ float gelu_fast(float x) {
    float s = x * fmaf(x * x, 0.07135481242f, 1.5957691216f);
    float e = __expf(-s);
    return x * __builtin_amdgcn_rcpf(1.0f + e);
}
// async global->LDS, 16B per lane. lds must be wave-uniform base; HW scatters
// lane i to base + i*16 (m97/m104). gptr is per-lane.
static __device__ __forceinline__ void gload16(void* lds, const void* g) {
    __builtin_amdgcn_global_load_lds(
        (const __attribute__((address_space(1))) unsigned int*)g,
        (__attribute__((address_space(3))) unsigned int*)lds, 16, 0, 0);
}

// ---------------------------------------------------------------------------
// Weight convert+transpose: W[K,N] f32 -> Wt[N,K] bf16. 32x32 LDS tiles.
// ---------------------------------------------------------------------------
__global__ __launch_bounds__(256) void cvt_t_kernel(
    const float* __restrict__ W, unsigned short* __restrict__ Wt, int K, int N)
{
    __shared__ unsigned short tile[32][33];
    int n0 = blockIdx.x * 32, k0 = blockIdx.y * 32;
    int tx = threadIdx.x & 31, ty = threadIdx.x >> 5;   // ty 0..7
#pragma unroll
    for (int p = 0; p < 32; p += 8)
        tile[tx][ty + p] = f2b(W[(size_t)(k0 + ty + p) * N + n0 + tx]);
    __syncthreads();
#pragma unroll
    for (int p = 0; p < 32; p += 8)
        Wt[(size_t)(n0 + ty + p) * K + k0 + tx] = tile[ty + p][tx];
}

// ---------------------------------------------------------------------------
// Concatenate three 512-float bias vectors into one 1536-float vector.
// ---------------------------------------------------------------------------
__global__ __launch_bounds__(256) void concat3_kernel(
    const float* __restrict__ a, const float* __restrict__ b,
    const float* __restrict__ c, float* __restrict__ o)
{
    int i = blockIdx.x * 256 + threadIdx.x;
    if (i < 512) { o[i] = a[i]; o[512 + i] = b[i]; o[1024 + i] = c[i]; }
}

// ---------------------------------------------------------------------------
// LayerNorm: f32 input rows of 512 -> bf16 output. One wave per row.
// ---------------------------------------------------------------------------
__global__ __launch_bounds__(256) void ln_kernel(
    const float* __restrict__ x,
    const float* __restrict__ g,
    const float* __restrict__ b,
    unsigned short* __restrict__ out, int rows)
{
    int row  = blockIdx.x * 4 + (threadIdx.x >> 6);
    int lane = threadIdx.x & 63;
    if (row >= rows) return;
    const float* xr = x + (size_t)row * 512 + lane * 8;
    float4 d0 = *(const float4*)xr;
    float4 d1 = *(const float4*)(xr + 4);
    float v[8] = {d0.x, d0.y, d0.z, d0.w, d1.x, d1.y, d1.z, d1.w};
    float s = 0.f, ss = 0.f;
#pragma unroll
    for (int j = 0; j < 8; ++j) { s += v[j]; ss += v[j] * v[j]; }
#pragma unroll
    for (int o = 32; o > 0; o >>= 1) { s += __shfl_xor(s, o); ss += __shfl_xor(ss, o); }
    float mu   = s * (1.0f / 512.0f);
    float var  = ss * (1.0f / 512.0f) - mu * mu;
    var = fmaxf(var, 0.0f);
    float rstd = rsqrtf(var + 1e-5f);
    float4 g0 = *(const float4*)(g + lane * 8);
    float4 g1 = *(const float4*)(g + lane * 8 + 4);
    float4 b0 = *(const float4*)(b + lane * 8);
    float4 b1 = *(const float4*)(b + lane * 8 + 4);
    float gg[8] = {g0.x, g0.y, g0.z, g0.w, g1.x, g1.y, g1.z, g1.w};
    float bb[8] = {b0.x, b0.y, b0.z, b0.w, b1.x, b1.y, b1.z, b1.w};
    uint4 res; unsigned short* rs = (unsigned short*)&res;
#pragma unroll
    for (int j = 0; j < 8; ++j)
        rs[j] = f2b((v[j] - mu) * rstd * gg[j] + bb[j]);
    *(uint4*)(out + (size_t)row * 512 + lane * 8) = res;
}

// ---------------------------------------------------------------------------
// Pipelined m97-style GEMM: C[M,N] = act(A[M,K] @ Bt[N,K]^T + bias) [+res]
// 128x128 tile, BK=32, 4 waves x (64x64 via 4x4 16x16x32 mfma).
// 4-buffer LDS ring, prefetch 3 tiles ahead via global_load_lds, counted
// s_waitcnt vmcnt(8) + one raw s_barrier per K-step.
// K-PHASE ROTATION (anti channel-camping): block row `by` starts its K loop
// at tile (by & (nt-1)) and wraps. Without this, all blocks fetch A at byte
// offset 64*t mod rowpitch in lockstep -> narrow HBM-channel band (~1 TB/s
// observed cap). Rotation spreads concurrent k-offsets over the full row
// period; same-by blocks share a phase so A-panel L3 reuse is preserved.
// Accumulation order over K changes (fp rounding only).
// XOR swizzle (kgrp ^= (row>>1)&3) baked into staging source; XCD-chunked
// blockIdx swizzle (bijective when nwg%8==0; guarded).
// ---------------------------------------------------------------------------
__global__ __launch_bounds__(256) void gemm_bt_kernel(
    const unsigned short* __restrict__ A,    // [M,K] bf16
    const unsigned short* __restrict__ Bt,   // [N,K] bf16
    const float* __restrict__ bias,
    const float* __restrict__ residual,
    void* __restrict__ Cv,
    int M, int N, int K, int act_gelu, int out_f32)
{
    __shared__ unsigned short As[4][128 * 32];
    __shared__ unsigned short Bs[4][128 * 32];

    const int tid  = threadIdx.x;
    const int wave = tid >> 6, lane = tid & 63;
    const int quad = lane >> 4, l16 = lane & 15;

    int bx = blockIdx.x, by = blockIdx.y;
    {
        int nwg = gridDim.x * gridDim.y;
        if ((nwg & 7) == 0) {
            int lid = by * gridDim.x + bx;
            int cpx = nwg >> 3;
            lid = (lid & 7) * cpx + (lid >> 3);
            bx = lid % gridDim.x;
            by = lid / gridDim.x;
        }
    }
    const int bm = by * 128, bn = bx * 128;
    const int wm = (wave >> 1) * 64, wn = (wave & 1) * 64;

    // staging: wave w, call c stages rows 16w+64c .. +16 of the tile.
    // lane i -> slot(row = 16w+64c+(i>>2), sgrp = i&3); source k-group is
    // swizzled: glog = sgrp ^ ((row>>1)&3)  (row+64 doesn't change the bits).
    const int srow = 16 * wave + (lane >> 2);
    const int sgrp = (lane & 3) ^ ((srow >> 1) & 3);
    const unsigned short* a_src = A  + (size_t)(bm + srow) * K + sgrp * 8;
    const unsigned short* b_src = Bt + (size_t)(bn + srow) * K + sgrp * 8;
    const size_t rowskip = (size_t)64 * K;
    const int wo = 512 * wave;                    // per-wave LDS stripe (elems)

    // fragment-read swizzle: for r = wm+i*16+l16, (r>>1)&3 == (l16>>1)&3.
    const int axor = ((quad ^ ((l16 >> 1) & 3)) * 8);

    f32x4 acc[4][4] = {};

    const int nt    = K >> 5;        // 32-col tiles; K in {512,2048} -> 16/64 (pow2)
    const int ntm   = nt - 1;
    const int phase = by & ntm;      // same-by blocks share phase (L3 reuse)

    // prologue: stage rotated tiles 0,1,2 (12 gloads/wave outstanding)
#pragma unroll
    for (int p = 0; p < 3; ++p) {
        int kp = ((p + phase) & ntm) << 5;
        gload16(As[p] + wo,        a_src + kp);
        gload16(As[p] + wo + 2048, a_src + rowskip + kp);
        gload16(Bs[p] + wo,        b_src + kp);
        gload16(Bs[p] + wo + 2048, b_src + rowskip + kp);
    }

    for (int t = 0; t < nt; ++t) {
        // own tile-t stage (issued at t-3) complete at <=8 outstanding
        asm volatile("s_waitcnt vmcnt(8)" ::: "memory");
        __builtin_amdgcn_s_barrier();          // all waves' tile-t stages done
        __builtin_amdgcn_sched_barrier(0);

        const unsigned short* Ar = As[t & 3];
        const unsigned short* Br = Bs[t & 3];
        s16x8 af[4], bfr[4];
#pragma unroll
        for (int i = 0; i < 4; ++i)
            af[i] = *(const s16x8*)&Ar[(wm + i * 16 + l16) * 32 + axor];
#pragma unroll
        for (int j = 0; j < 4; ++j)
            bfr[j] = *(const s16x8*)&Bs[t & 3][(wn + j * 16 + l16) * 32 + axor];

        // prefetch tile t+3 (wraps at tail: duplicate loads, never-read slot
        // contents; keeps the vmcnt invariant without dummies)
        {
            int kp = ((t + 3 + phase) & ntm) << 5;
            unsigned short* Aw = As[(t + 3) & 3];
            unsigned short* Bw = Bs[(t + 3) & 3];
            gload16(Aw + wo,        a_src + kp);
            gload16(Aw + wo + 2048, a_src + rowskip + kp);
            gload16(Bw + wo,        b_src + kp);
            gload16(Bw + wo + 2048, b_src + rowskip + kp);
        }

#pragma unroll
        for (int i = 0; i < 4; ++i)
#pragma unroll
            for (int j = 0; j < 4; ++j)
                acc[i][j] = __builtin_amdgcn_mfma_f32_16x16x32_bf16(af[i], bfr[j], acc[i][j], 0, 0, 0);
    }
    // drain wrapped stages so no gload_lds write lands after LDS dealloc
    asm volatile("s_waitcnt vmcnt(0)" ::: "memory");

#pragma unroll
    for (int i = 0; i < 4; ++i) {
#pragma unroll
        for (int j = 0; j < 4; ++j) {
#pragma unroll
            for (int r = 0; r < 4; ++r) {
                int row = bm + wm + i * 16 + quad * 4 + r;
                int col = bn + wn + j * 16 + l16;
                float val = acc[i][j][r] + bias[col];
                if (act_gelu) val = gelu_fast(val);
                if (residual) val += residual[(size_t)row * N + col];
                if (out_f32) ((float*)Cv)[(size_t)row * N + col] = val;
                else ((unsigned short*)Cv)[(size_t)row * N + col] = f2b(val);
            }
        }
    }
}

// ---------------------------------------------------------------------------
// Attention: one block per batch. qkv packed [T,1536] bf16 (q|k|v),
// x residual f32, x2 out f32.
// Ps/Vs LDS tiles XOR-swizzled: 256B row stride makes unswizzled column
// reads a 16-way bank conflict (G4); swizzle spreads each quad's 16 lanes
// across 8 16B slots (2-way = free, m136).
// ---------------------------------------------------------------------------
__global__ __launch_bounds__(256) void attn_kernel(
    const unsigned short* __restrict__ qkv,
    const float* __restrict__ x,
    float* __restrict__ x2)
{
    __shared__ unsigned short Ps[128][128];
    __shared__ unsigned short Vs[64][128];

    int b = blockIdx.x;
    int tid = threadIdx.x;
    int wave = tid >> 6, lane = tid & 63;
    int quad = lane >> 4, l16 = lane & 15;
    const unsigned short* qb = qkv + (size_t)b * 128 * 1536;   // q at +0, k at +512, v at +1024
    const size_t bo = (size_t)b * 128 * 512;

    f32x4 acc[2][8] = {};
    for (int e0 = 0; e0 < 512; e0 += 32) {
        s16x8 a0 = *(const s16x8*)(qb + (size_t)(wave * 32 + l16) * 1536 + e0 + quad * 8);
        s16x8 a1 = *(const s16x8*)(qb + (size_t)(wave * 32 + 16 + l16) * 1536 + e0 + quad * 8);
#pragma unroll
        for (int j = 0; j < 8; ++j) {
            s16x8 bf = *(const s16x8*)(qb + (size_t)(j * 16 + l16) * 1536 + 512 + e0 + quad * 8);
            acc[0][j] = __builtin_amdgcn_mfma_f32_16x16x32_bf16(a0, bf, acc[0][j], 0, 0, 0);
            acc[1][j] = __builtin_amdgcn_mfma_f32_16x16x32_bf16(a1, bf, acc[1][j], 0, 0, 0);
        }
    }

    const float NEG = -1e30f;
#pragma unroll
    for (int i = 0; i < 2; ++i) {
#pragma unroll
        for (int r = 0; r < 4; ++r) {
            int t = wave * 32 + i * 16 + quad * 4 + r;
            float m = NEG;
#pragma unroll
            for (int j = 0; j < 8; ++j) {
                int s_col = j * 16 + l16;
                float val = acc[i][j][r] * 0.125f;
                val = (s_col <= t) ? val : NEG;
                acc[i][j][r] = val;
                m = fmaxf(m, val);
            }
            for (int o = 1; o < 16; o <<= 1) m = fmaxf(m, __shfl_xor(m, o));
            float sm = 0.f;
#pragma unroll
            for (int j = 0; j < 8; ++j) {
                float e = __expf(acc[i][j][r] - m);
                acc[i][j][r] = e;
                sm += e;
            }
            for (int o = 1; o < 16; o <<= 1) sm += __shfl_xor(sm, o);
            float inv = 1.0f / sm;
#pragma unroll
            for (int j = 0; j < 8; ++j) {
                // col c = j*16+l16; swizzled 16B-group: g ^= (t&7)
                int g = (j * 2 + (l16 >> 3)) ^ (t & 7);
                Ps[t][g * 8 + (l16 & 7)] = f2b(acc[i][j][r] * inv);
            }
        }
    }
    __syncthreads();

    const float* xb = x + bo;
    float* ob = x2 + bo;
    for (int e0 = 0; e0 < 512; e0 += 64) {
        if (e0) __syncthreads();
#pragma unroll
        for (int p = 0; p < 4; ++p) {
            int s = (tid >> 3) + p * 32;
            int c = (tid & 7) * 8;
            uint4 d = *(const uint4*)(qb + (size_t)s * 1536 + 1024 + e0 + c);
            const unsigned short* dsv = (const unsigned short*)&d;
#pragma unroll
            for (int j = 0; j < 8; ++j) {
                int rr = c + j;   // rr&7 == j, rr>>3 == tid&7
                int g = (s >> 3) ^ j ^ (tid & 7);
                Vs[rr][g * 8 + (s & 7)] = dsv[j];
            }
        }
        __syncthreads();

        f32x4 acc2[2][4] = {};
#pragma unroll
        for (int ks = 0; ks < 4; ++ks) {
            // Ps rows wave*32(+16)+l16: row&7 == l16&7 for both
            int gp = ((ks * 4 + quad) ^ (l16 & 7)) * 8;
            s16x8 a0 = *(const s16x8*)(&Ps[wave * 32 + l16][gp]);
            s16x8 a1 = *(const s16x8*)(&Ps[wave * 32 + 16 + l16][gp]);
#pragma unroll
            for (int n = 0; n < 4; ++n) {
                // Vs row n*16+l16: row&7 == l16&7, row>>3 == 2n+(l16>>3)
                int gv = ((ks * 4 + quad) ^ (l16 & 7) ^ ((2 * n + (l16 >> 3)) & 7)) * 8;
                s16x8 bf = *(const s16x8*)(&Vs[n * 16 + l16][gv]);
                acc2[0][n] = __builtin_amdgcn_mfma_f32_16x16x32_bf16(a0, bf, acc2[0][n], 0, 0, 0);
                acc2[1][n] = __builtin_amdgcn_mfma_f32_16x16x32_bf16(a1, bf, acc2[1][n], 0, 0, 0);
            }
        }
#pragma unroll
        for (int i = 0; i < 2; ++i) {
#pragma unroll
            for (int n = 0; n < 4; ++n) {
#pragma unroll
                for (int r = 0; r < 4; ++r) {
                    int t = wave * 32 + i * 16 + quad * 4 + r;
                    int e = e0 + n * 16 + l16;
                    ob[(size_t)t * 512 + e] = acc2[i][n][r] + xb[(size_t)t * 512 + e];
                }
            }
        }
    }
}

// ---------------------------------------------------------------------------
extern "C" void kernel_launch(void* const* d_in, const int* in_sizes, int n_in,
                              void* d_out, int out_size, void* d_ws, size_t ws_size,
                              hipStream_t stream) {
    const float* x   = (const float*)d_in[0];
    const float* wq  = (const float*)d_in[1];
    const float* bq  = (const float*)d_in[2];
    const float* wk  = (const float*)d_in[3];
    const float* bk  = (const float*)d_in[4];
    const float* wv  = (const float*)d_in[5];
    const float* bv  = (const float*)d_in[6];
    const float* g1  = (const float*)d_in[7];
    const float* b1  = (const float*)d_in[8];
    const float* g2  = (const float*)d_in[9];
    const float* b2  = (const float*)d_in[10];
    const float* w1  = (const float*)d_in[11];
    const float* bm1 = (const float*)d_in[12];
    const float* w2  = (const float*)d_in[13];
    const float* bm2 = (const float*)d_in[14];
    float* out = (float*)d_out;          // reference output dtype is float32

    const int BATCH = 512, T = 128;
    dim3 blk(256);

    // ---- one-time weight convert+transpose f32[K,N] -> bf16[N,K] ----
    // wqt/wkt/wvt are contiguous => together they form Wqkv_t [1536, 512].
    unsigned short* wqt = (unsigned short*)d_ws;
    unsigned short* wkt = wqt + 262144;
    unsigned short* wvt = wkt + 262144;
    unsigned short* w1t = wvt + 262144;   // [2048, 512]
    unsigned short* w2t = w1t + 1048576;  // [512, 2048]
    float* bqkv = (float*)(w2t + 1048576); // [1536] concat bias
    cvt_t_kernel<<<dim3(16, 16), blk, 0, stream>>>(wq, wqt, 512, 512);
    cvt_t_kernel<<<dim3(16, 16), blk, 0, stream>>>(wk, wkt, 512, 512);
    cvt_t_kernel<<<dim3(16, 16), blk, 0, stream>>>(wv, wvt, 512, 512);
    cvt_t_kernel<<<dim3(64, 16), blk, 0, stream>>>(w1, w1t, 512, 2048);
    cvt_t_kernel<<<dim3(16, 64), blk, 0, stream>>>(w2, w2t, 2048, 512);
    concat3_kernel<<<dim3(2), blk, 0, stream>>>(bq, bk, bv, bqkv);

    // ---- dynamic region: chunk batch so it fits ws ----
    // per-batch bytes: h bf16 (131072) + x2f f32 (262144) + slab (524288)
    //  = 917504; plus 5773312 B of converted weights+bias.
    int C = 512;
    while (C > 1 && 5773312ull + (size_t)C * 917504ull > ws_size) C >>= 1;

    const int R = C * T;                 // rows per chunk (multiple of 128)
    const size_t S = (size_t)R * 512;    // elements per 512-wide row buffer
    char* dyn = (char*)(bqkv + 1536);
    unsigned short* h   = (unsigned short*)dyn;
    float*          x2f = (float*)(dyn + S * 2);
    unsigned short* qkv = (unsigned short*)(dyn + S * 2 + S * 4);  // [R,1536] bf16 (6S bytes)
    unsigned short* mff = qkv;           // aliases qkv after attention; 4*S elems (8S bytes)

    for (int b0 = 0; b0 < BATCH; b0 += C) {
        const size_t off = (size_t)b0 * T * 512;
        // attention sub-block
        ln_kernel<<<R / 4, blk, 0, stream>>>(x + off, g1, b1, h, R);
        gemm_bt_kernel<<<dim3(12, R / 128), blk, 0, stream>>>(h, wqt, bqkv, nullptr, qkv, R, 1536, 512, 0, 0);
        attn_kernel<<<C, blk, 0, stream>>>(qkv, x + off, x2f);
        // MLP sub-block
        ln_kernel<<<R / 4, blk, 0, stream>>>(x2f, g2, b2, h, R);
        gemm_bt_kernel<<<dim3(16, R / 128), blk, 0, stream>>>(h, w1t, bm1, nullptr, mff, R, 2048, 512, 1, 0);
        gemm_bt_kernel<<<dim3(4, R / 128), blk, 0, stream>>>(mff, w2t, bm2, x2f, out + off, R, 512, 2048, 0, 1);
    }
}

// Round 5
// 1050.036 us; speedup vs baseline: 1.1494x; 1.1494x over previous
//
#include <hip/hip_runtime.h>
#include <hip/hip_bf16.h>
#include <math.h>

typedef __attribute__((ext_vector_type(8))) short s16x8;
typedef __attribute__((ext_vector_type(4))) float f32x4;

static __device__ __forceinline__ float b2f(unsigned short u) {
    union { unsigned int u; float f; } x; x.u = ((unsigned int)u) << 16; return x.f;
}
static __device__ __forceinline__ unsigned short f2b(float f) {
    __hip_bfloat16 h = __float2bfloat16(f);
    return *reinterpret_cast<unsigned short*>(&h);
}
// tanh-approx GELU in sigmoid form: x * sigmoid(1.5957691*x*(1+0.044715*x^2)).
static __device__ __forceinline__ float gelu_fast(float x) {
    float s = x * fmaf(x * x, 0.07135481242f, 1.5957691216f);
    float e = __expf(-s);
    return x * __builtin_amdgcn_rcpf(1.0f + e);
}
// async global->LDS, 16B per lane. lds must be wave-uniform base; HW scatters
// lane i to base + i*16 (m97/m104). gptr is per-lane.
static __device__ __forceinline__ void gload16(void* lds, const void* g) {
    __builtin_amdgcn_global_load_lds(
        (const __attribute__((address_space(1))) unsigned int*)g,
        (__attribute__((address_space(3))) unsigned int*)lds, 16, 0, 0);
}

// ---------------------------------------------------------------------------
// Weight convert+transpose: W[K,N] f32 -> Wt[N,K] bf16. 32x32 LDS tiles.
// ---------------------------------------------------------------------------
__global__ __launch_bounds__(256) void cvt_t_kernel(
    const float* __restrict__ W, unsigned short* __restrict__ Wt, int K, int N)
{
    __shared__ unsigned short tile[32][33];
    int n0 = blockIdx.x * 32, k0 = blockIdx.y * 32;
    int tx = threadIdx.x & 31, ty = threadIdx.x >> 5;
#pragma unroll
    for (int p = 0; p < 32; p += 8)
        tile[tx][ty + p] = f2b(W[(size_t)(k0 + ty + p) * N + n0 + tx]);
    __syncthreads();
#pragma unroll
    for (int p = 0; p < 32; p += 8)
        Wt[(size_t)(n0 + ty + p) * K + k0 + tx] = tile[ty + p][tx];
}

// ---------------------------------------------------------------------------
__global__ __launch_bounds__(256) void concat3_kernel(
    const float* __restrict__ a, const float* __restrict__ b,
    const float* __restrict__ c, float* __restrict__ o)
{
    int i = blockIdx.x * 256 + threadIdx.x;
    if (i < 512) { o[i] = a[i]; o[512 + i] = b[i]; o[1024 + i] = c[i]; }
}

// ---------------------------------------------------------------------------
// LayerNorm: f32 input rows of 512 -> bf16 output. One wave per row.
// ---------------------------------------------------------------------------
__global__ __launch_bounds__(256) void ln_kernel(
    const float* __restrict__ x,
    const float* __restrict__ g,
    const float* __restrict__ b,
    unsigned short* __restrict__ out, int rows)
{
    int row  = blockIdx.x * 4 + (threadIdx.x >> 6);
    int lane = threadIdx.x & 63;
    if (row >= rows) return;
    const float* xr = x + (size_t)row * 512 + lane * 8;
    float4 d0 = *(const float4*)xr;
    float4 d1 = *(const float4*)(xr + 4);
    float v[8] = {d0.x, d0.y, d0.z, d0.w, d1.x, d1.y, d1.z, d1.w};
    float s = 0.f, ss = 0.f;
#pragma unroll
    for (int j = 0; j < 8; ++j) { s += v[j]; ss += v[j] * v[j]; }
#pragma unroll
    for (int o = 32; o > 0; o >>= 1) { s += __shfl_xor(s, o); ss += __shfl_xor(ss, o); }
    float mu   = s * (1.0f / 512.0f);
    float var  = ss * (1.0f / 512.0f) - mu * mu;
    var = fmaxf(var, 0.0f);
    float rstd = rsqrtf(var + 1e-5f);
    float4 g0 = *(const float4*)(g + lane * 8);
    float4 g1 = *(const float4*)(g + lane * 8 + 4);
    float4 b0 = *(const float4*)(b + lane * 8);
    float4 b1 = *(const float4*)(b + lane * 8 + 4);
    float gg[8] = {g0.x, g0.y, g0.z, g0.w, g1.x, g1.y, g1.z, g1.w};
    float bb[8] = {b0.x, b0.y, b0.z, b0.w, b1.x, b1.y, b1.z, b1.w};
    uint4 res; unsigned short* rs = (unsigned short*)&res;
#pragma unroll
    for (int j = 0; j < 8; ++j)
        rs[j] = f2b((v[j] - mu) * rstd * gg[j] + bb[j]);
    *(uint4*)(out + (size_t)row * 512 + lane * 8) = res;
}

// ---------------------------------------------------------------------------
// 8-phase 256x256 GEMM (m201 template port): C = act(A @ Bt^T + bias) [+res]
// BK=64 split into 2 k-halves; 512 threads = 8 waves (2M x 4N), per-wave
// 128x64 output via acc[8][4] 16x16x32 mfma. LDS 128 KiB:
// [buf2][op A/B][khalf2][256 rows][32] bf16. Per K-tile, 4 phases:
//   {ds_read subtile (8 or 4 b128) ; stage 1 half-tile (2 gload_lds) ;
//    sched_barrier ; s_barrier ; setprio(1) ; 16 MFMA ; setprio(0) ; barrier}
// Stage order Ak0,Bk0,Ak1,Bk1 (tile t+1) matches consumption order; counted
// s_waitcnt vmcnt(4) at phases 1 & 3 ONLY (loads stay in flight across
// barriers, never drained to 0 in the loop  — T3+T4). Bank swizzle: 16B
// group ^= ((row>>1)&3) applied to stage SOURCE and read addr (involution,
// both-sides rule); 8 banks x 2 lanes = conflict-free.
// XCD-chunked blockIdx swizzle (bijective when nwg%8==0; guarded).
// ---------------------------------------------------------------------------
__global__ __launch_bounds__(512, 2) void gemm_bt_kernel(
    const unsigned short* __restrict__ A,    // [M,K] bf16
    const unsigned short* __restrict__ Bt,   // [N,K] bf16
    const float* __restrict__ bias,
    const float* __restrict__ residual,
    void* __restrict__ Cv,
    int M, int N, int K, int act_gelu, int out_f32)
{
    __shared__ unsigned short Lds[2][2][2][256][32];   // 131072 B

    const int tid  = threadIdx.x;
    const int w    = tid >> 6, lane = tid & 63;
    const int quad = lane >> 4, l16 = lane & 15;
    const int wm8  = w >> 2, wn8 = w & 3;              // 2 x 4 wave grid

    int bx = blockIdx.x, by = blockIdx.y;
    {
        int nwg = gridDim.x * gridDim.y;
        if ((nwg & 7) == 0) {
            int lid = by * gridDim.x + bx;
            int cpx = nwg >> 3;
            lid = (lid & 7) * cpx + (lid >> 3);
            bx = lid % gridDim.x;
            by = lid / gridDim.x;
        }
    }
    const int bm = by * 256, bn = bx * 256;

    // staging: thread -> (row = c*128 + w*16 + (l>>2), grp = l&3) of a
    // [256][32] half-tile; source k-group = (l&3) ^ ((l>>3)&3) (swizzle:
    // (row>>1)&3 == (l>>3)&3 for this mapping).
    const int srow = w * 16 + (lane >> 2);
    const int sg   = (lane & 3) ^ ((lane >> 3) & 3);
    const unsigned short* a_src = A  + (size_t)(bm + srow) * K + sg * 8;
    const unsigned short* b_src = Bt + (size_t)(bn + srow) * K + sg * 8;
    const size_t cskip = (size_t)128 * K;

    // fragment-read swizzle: for row = 16*base + l16, (row>>1)&3 == (l16>>1)&3
    const int axor = (quad ^ ((l16 >> 1) & 3)) * 8;

    f32x4 acc[8][4] = {};

    const int nt = K >> 6;     // K-tiles of 64: 8 (K=512) / 32 (K=2048)

    auto STG = [&](int buf, int op, int kh, int kt) {
        const unsigned short* src = op ? b_src : a_src;
        const int ko = kt * 64 + kh * 32;
        gload16(&Lds[buf][op][kh][w * 16][0],       src + ko);
        gload16(&Lds[buf][op][kh][128 + w * 16][0], src + cskip + ko);
    };

    // prologue: tile 0's four halves in steady-state order
    STG(0, 0, 0, 0); STG(0, 1, 0, 0); STG(0, 0, 1, 0); STG(0, 1, 1, 0);
    asm volatile("s_waitcnt vmcnt(4)" ::: "memory");   // Ak0,Bk0 landed
    __builtin_amdgcn_s_barrier();

    for (int t = 0; t < nt; ++t) {
        const int buf = t & 1, nb = buf ^ 1;
        const int ktn = (t + 1 < nt) ? t + 1 : 0;      // tail: dummy stage
        s16x8 a4[4], b4[4];

        // ---- phase 0: k-half 0, mrep 0-3 (+ all B k0) ----
#pragma unroll
        for (int m = 0; m < 4; ++m)
            a4[m] = *(const s16x8*)&Lds[buf][0][0][wm8 * 128 + m * 16 + l16][axor];
#pragma unroll
        for (int n = 0; n < 4; ++n)
            b4[n] = *(const s16x8*)&Lds[buf][1][0][wn8 * 64 + n * 16 + l16][axor];
        STG(nb, 0, 0, ktn);
        __builtin_amdgcn_sched_barrier(0);
        __builtin_amdgcn_s_barrier();
        __builtin_amdgcn_sched_barrier(0);
        __builtin_amdgcn_s_setprio(1);
#pragma unroll
        for (int m = 0; m < 4; ++m)
#pragma unroll
            for (int n = 0; n < 4; ++n)
                acc[m][n] = __builtin_amdgcn_mfma_f32_16x16x32_bf16(a4[m], b4[n], acc[m][n], 0, 0, 0);
        __builtin_amdgcn_s_setprio(0);
        __builtin_amdgcn_sched_barrier(0);
        __builtin_amdgcn_s_barrier();

        // ---- phase 1: k-half 0, mrep 4-7 ----
#pragma unroll
        for (int m = 0; m < 4; ++m)
            a4[m] = *(const s16x8*)&Lds[buf][0][0][wm8 * 128 + (m + 4) * 16 + l16][axor];
        STG(nb, 1, 0, ktn);
        __builtin_amdgcn_sched_barrier(0);
        __builtin_amdgcn_s_barrier();
        __builtin_amdgcn_sched_barrier(0);
        __builtin_amdgcn_s_setprio(1);
#pragma unroll
        for (int m = 0; m < 4; ++m)
#pragma unroll
            for (int n = 0; n < 4; ++n)
                acc[m + 4][n] = __builtin_amdgcn_mfma_f32_16x16x32_bf16(a4[m], b4[n], acc[m + 4][n], 0, 0, 0);
        __builtin_amdgcn_s_setprio(0);
        asm volatile("s_waitcnt vmcnt(4)" ::: "memory");  // this tile's Ak1,Bk1 landed
        __builtin_amdgcn_sched_barrier(0);
        __builtin_amdgcn_s_barrier();

        // ---- phase 2: k-half 1, mrep 0-3 (+ all B k1) ----
#pragma unroll
        for (int m = 0; m < 4; ++m)
            a4[m] = *(const s16x8*)&Lds[buf][0][1][wm8 * 128 + m * 16 + l16][axor];
#pragma unroll
        for (int n = 0; n < 4; ++n)
            b4[n] = *(const s16x8*)&Lds[buf][1][1][wn8 * 64 + n * 16 + l16][axor];
        STG(nb, 0, 1, ktn);
        __builtin_amdgcn_sched_barrier(0);
        __builtin_amdgcn_s_barrier();
        __builtin_amdgcn_sched_barrier(0);
        __builtin_amdgcn_s_setprio(1);
#pragma unroll
        for (int m = 0; m < 4; ++m)
#pragma unroll
            for (int n = 0; n < 4; ++n)
                acc[m][n] = __builtin_amdgcn_mfma_f32_16x16x32_bf16(a4[m], b4[n], acc[m][n], 0, 0, 0);
        __builtin_amdgcn_s_setprio(0);
        __builtin_amdgcn_sched_barrier(0);
        __builtin_amdgcn_s_barrier();

        // ---- phase 3: k-half 1, mrep 4-7 ----
#pragma unroll
        for (int m = 0; m < 4; ++m)
            a4[m] = *(const s16x8*)&Lds[buf][0][1][wm8 * 128 + (m + 4) * 16 + l16][axor];
        STG(nb, 1, 1, ktn);
        __builtin_amdgcn_sched_barrier(0);
        __builtin_amdgcn_s_barrier();
        __builtin_amdgcn_sched_barrier(0);
        __builtin_amdgcn_s_setprio(1);
#pragma unroll
        for (int m = 0; m < 4; ++m)
#pragma unroll
            for (int n = 0; n < 4; ++n)
                acc[m + 4][n] = __builtin_amdgcn_mfma_f32_16x16x32_bf16(a4[m], b4[n], acc[m + 4][n], 0, 0, 0);
        __builtin_amdgcn_s_setprio(0);
        asm volatile("s_waitcnt vmcnt(4)" ::: "memory");  // next tile's Ak0,Bk0 landed
        __builtin_amdgcn_sched_barrier(0);
        __builtin_amdgcn_s_barrier();
    }
    asm volatile("s_waitcnt vmcnt(0)" ::: "memory");   // drain dummy stages

#pragma unroll
    for (int m = 0; m < 8; ++m) {
#pragma unroll
        for (int n = 0; n < 4; ++n) {
#pragma unroll
            for (int r = 0; r < 4; ++r) {
                int row = bm + wm8 * 128 + m * 16 + quad * 4 + r;
                int col = bn + wn8 * 64 + n * 16 + l16;
                float val = acc[m][n][r] + bias[col];
                if (act_gelu) val = gelu_fast(val);
                if (residual) val += residual[(size_t)row * N + col];
                if (out_f32) ((float*)Cv)[(size_t)row * N + col] = val;
                else ((unsigned short*)Cv)[(size_t)row * N + col] = f2b(val);
            }
        }
    }
}

// ---------------------------------------------------------------------------
// Attention: one block per batch. qkv packed [T,1536] bf16 (q|k|v),
// x residual f32, x2 out f32. Ps/Vs LDS XOR-swizzled (conflict-free).
// ---------------------------------------------------------------------------
__global__ __launch_bounds__(256) void attn_kernel(
    const unsigned short* __restrict__ qkv,
    const float* __restrict__ x,
    float* __restrict__ x2)
{
    __shared__ unsigned short Ps[128][128];
    __shared__ unsigned short Vs[64][128];

    int b = blockIdx.x;
    int tid = threadIdx.x;
    int wave = tid >> 6, lane = tid & 63;
    int quad = lane >> 4, l16 = lane & 15;
    const unsigned short* qb = qkv + (size_t)b * 128 * 1536;
    const size_t bo = (size_t)b * 128 * 512;

    f32x4 acc[2][8] = {};
    for (int e0 = 0; e0 < 512; e0 += 32) {
        s16x8 a0 = *(const s16x8*)(qb + (size_t)(wave * 32 + l16) * 1536 + e0 + quad * 8);
        s16x8 a1 = *(const s16x8*)(qb + (size_t)(wave * 32 + 16 + l16) * 1536 + e0 + quad * 8);
#pragma unroll
        for (int j = 0; j < 8; ++j) {
            s16x8 bf = *(const s16x8*)(qb + (size_t)(j * 16 + l16) * 1536 + 512 + e0 + quad * 8);
            acc[0][j] = __builtin_amdgcn_mfma_f32_16x16x32_bf16(a0, bf, acc[0][j], 0, 0, 0);
            acc[1][j] = __builtin_amdgcn_mfma_f32_16x16x32_bf16(a1, bf, acc[1][j], 0, 0, 0);
        }
    }

    const float NEG = -1e30f;
#pragma unroll
    for (int i = 0; i < 2; ++i) {
#pragma unroll
        for (int r = 0; r < 4; ++r) {
            int t = wave * 32 + i * 16 + quad * 4 + r;
            float m = NEG;
#pragma unroll
            for (int j = 0; j < 8; ++j) {
                int s_col = j * 16 + l16;
                float val = acc[i][j][r] * 0.125f;
                val = (s_col <= t) ? val : NEG;
                acc[i][j][r] = val;
                m = fmaxf(m, val);
            }
            for (int o = 1; o < 16; o <<= 1) m = fmaxf(m, __shfl_xor(m, o));
            float sm = 0.f;
#pragma unroll
            for (int j = 0; j < 8; ++j) {
                float e = __expf(acc[i][j][r] - m);
                acc[i][j][r] = e;
                sm += e;
            }
            for (int o = 1; o < 16; o <<= 1) sm += __shfl_xor(sm, o);
            float inv = 1.0f / sm;
#pragma unroll
            for (int j = 0; j < 8; ++j) {
                int g = (j * 2 + (l16 >> 3)) ^ (t & 7);
                Ps[t][g * 8 + (l16 & 7)] = f2b(acc[i][j][r] * inv);
            }
        }
    }
    __syncthreads();

    const float* xb = x + bo;
    float* ob = x2 + bo;
    for (int e0 = 0; e0 < 512; e0 += 64) {
        if (e0) __syncthreads();
#pragma unroll
        for (int p = 0; p < 4; ++p) {
            int s = (tid >> 3) + p * 32;
            int c = (tid & 7) * 8;
            uint4 d = *(const uint4*)(qb + (size_t)s * 1536 + 1024 + e0 + c);
            const unsigned short* dsv = (const unsigned short*)&d;
#pragma unroll
            for (int j = 0; j < 8; ++j) {
                int rr = c + j;
                int g = (s >> 3) ^ j ^ (tid & 7);
                Vs[rr][g * 8 + (s & 7)] = dsv[j];
            }
        }
        __syncthreads();

        f32x4 acc2[2][4] = {};
#pragma unroll
        for (int ks = 0; ks < 4; ++ks) {
            int gp = ((ks * 4 + quad) ^ (l16 & 7)) * 8;
            s16x8 a0 = *(const s16x8*)(&Ps[wave * 32 + l16][gp]);
            s16x8 a1 = *(const s16x8*)(&Ps[wave * 32 + 16 + l16][gp]);
#pragma unroll
            for (int n = 0; n < 4; ++n) {
                int gv = ((ks * 4 + quad) ^ (l16 & 7) ^ ((2 * n + (l16 >> 3)) & 7)) * 8;
                s16x8 bf = *(const s16x8*)(&Vs[n * 16 + l16][gv]);
                acc2[0][n] = __builtin_amdgcn_mfma_f32_16x16x32_bf16(a0, bf, acc2[0][n], 0, 0, 0);
                acc2[1][n] = __builtin_amdgcn_mfma_f32_16x16x32_bf16(a1, bf, acc2[1][n], 0, 0, 0);
            }
        }
#pragma unroll
        for (int i = 0; i < 2; ++i) {
#pragma unroll
            for (int n = 0; n < 4; ++n) {
#pragma unroll
                for (int r = 0; r < 4; ++r) {
                    int t = wave * 32 + i * 16 + quad * 4 + r;
                    int e = e0 + n * 16 + l16;
                    ob[(size_t)t * 512 + e] = acc2[i][n][r] + xb[(size_t)t * 512 + e];
                }
            }
        }
    }
}

// ---------------------------------------------------------------------------
extern "C" void kernel_launch(void* const* d_in, const int* in_sizes, int n_in,
                              void* d_out, int out_size, void* d_ws, size_t ws_size,
                              hipStream_t stream) {
    const float* x   = (const float*)d_in[0];
    const float* wq  = (const float*)d_in[1];
    const float* bq  = (const float*)d_in[2];
    const float* wk  = (const float*)d_in[3];
    const float* bk  = (const float*)d_in[4];
    const float* wv  = (const float*)d_in[5];
    const float* bv  = (const float*)d_in[6];
    const float* g1  = (const float*)d_in[7];
    const float* b1  = (const float*)d_in[8];
    const float* g2  = (const float*)d_in[9];
    const float* b2  = (const float*)d_in[10];
    const float* w1  = (const float*)d_in[11];
    const float* bm1 = (const float*)d_in[12];
    const float* w2  = (const float*)d_in[13];
    const float* bm2 = (const float*)d_in[14];
    float* out = (float*)d_out;

    const int BATCH = 512, T = 128;
    dim3 blk(256), blkg(512);

    // ---- one-time weight convert+transpose f32[K,N] -> bf16[N,K] ----
    unsigned short* wqt = (unsigned short*)d_ws;
    unsigned short* wkt = wqt + 262144;
    unsigned short* wvt = wkt + 262144;
    unsigned short* w1t = wvt + 262144;   // [2048, 512]
    unsigned short* w2t = w1t + 1048576;  // [512, 2048]
    float* bqkv = (float*)(w2t + 1048576);
    cvt_t_kernel<<<dim3(16, 16), blk, 0, stream>>>(wq, wqt, 512, 512);
    cvt_t_kernel<<<dim3(16, 16), blk, 0, stream>>>(wk, wkt, 512, 512);
    cvt_t_kernel<<<dim3(16, 16), blk, 0, stream>>>(wv, wvt, 512, 512);
    cvt_t_kernel<<<dim3(64, 16), blk, 0, stream>>>(w1, w1t, 512, 2048);
    cvt_t_kernel<<<dim3(16, 64), blk, 0, stream>>>(w2, w2t, 2048, 512);
    concat3_kernel<<<dim3(2), blk, 0, stream>>>(bq, bk, bv, bqkv);

    // ---- dynamic region: chunk batch so it fits ws (C even -> R%256==0) ----
    int C = 512;
    while (C > 4 && 5773312ull + (size_t)C * 917504ull > ws_size) C >>= 1;

    const int R = C * T;
    const size_t S = (size_t)R * 512;
    char* dyn = (char*)(bqkv + 1536);
    unsigned short* h   = (unsigned short*)dyn;
    float*          x2f = (float*)(dyn + S * 2);
    unsigned short* qkv = (unsigned short*)(dyn + S * 2 + S * 4);
    unsigned short* mff = qkv;

    for (int b0 = 0; b0 < BATCH; b0 += C) {
        const size_t off = (size_t)b0 * T * 512;
        // attention sub-block
        ln_kernel<<<R / 4, blk, 0, stream>>>(x + off, g1, b1, h, R);
        gemm_bt_kernel<<<dim3(6, R / 256), blkg, 0, stream>>>(h, wqt, bqkv, nullptr, qkv, R, 1536, 512, 0, 0);
        attn_kernel<<<C, blk, 0, stream>>>(qkv, x + off, x2f);
        // MLP sub-block
        ln_kernel<<<R / 4, blk, 0, stream>>>(x2f, g2, b2, h, R);
        gemm_bt_kernel<<<dim3(8, R / 256), blkg, 0, stream>>>(h, w1t, bm1, nullptr, mff, R, 2048, 512, 1, 0);
        gemm_bt_kernel<<<dim3(2, R / 256), blkg, 0, stream>>>(mff, w2t, bm2, x2f, out + off, R, 512, 2048, 0, 1);
    }
}

// Round 6
// 1024.138 us; speedup vs baseline: 1.1785x; 1.0253x over previous
//
#include <hip/hip_runtime.h>
#include <hip/hip_bf16.h>
#include <math.h>

typedef __attribute__((ext_vector_type(8))) short s16x8;
typedef __attribute__((ext_vector_type(4))) float f32x4;

static __device__ __forceinline__ float b2f(unsigned short u) {
    union { unsigned int u; float f; } x; x.u = ((unsigned int)u) << 16; return x.f;
}
static __device__ __forceinline__ unsigned short f2b(float f) {
    __hip_bfloat16 h = __float2bfloat16(f);
    return *reinterpret_cast<unsigned short*>(&h);
}
// tanh-approx GELU in sigmoid form: x * sigmoid(1.5957691*x*(1+0.044715*x^2)).
static __device__ __forceinline__ float gelu_fast(float x) {
    float s = x * fmaf(x * x, 0.07135481242f, 1.5957691216f);
    float e = __expf(-s);
    return x * __builtin_amdgcn_rcpf(1.0f + e);
}
// async global->LDS, 16B per lane. lds must be wave-uniform base; HW scatters
// lane i to base + i*16 (m97/m104). gptr is per-lane.
static __device__ __forceinline__ void gload16(void* lds, const void* g) {
    __builtin_amdgcn_global_load_lds(
        (const __attribute__((address_space(1))) unsigned int*)g,
        (__attribute__((address_space(3))) unsigned int*)lds, 16, 0, 0);
}

// ---------------------------------------------------------------------------
// Weight convert+transpose: W[K,N] f32 -> Wt[N,K] bf16. 32x32 LDS tiles.
// ---------------------------------------------------------------------------
__global__ __launch_bounds__(256) void cvt_t_kernel(
    const float* __restrict__ W, unsigned short* __restrict__ Wt, int K, int N)
{
    __shared__ unsigned short tile[32][33];
    int n0 = blockIdx.x * 32, k0 = blockIdx.y * 32;
    int tx = threadIdx.x & 31, ty = threadIdx.x >> 5;
#pragma unroll
    for (int p = 0; p < 32; p += 8)
        tile[tx][ty + p] = f2b(W[(size_t)(k0 + ty + p) * N + n0 + tx]);
    __syncthreads();
#pragma unroll
    for (int p = 0; p < 32; p += 8)
        Wt[(size_t)(n0 + ty + p) * K + k0 + tx] = tile[ty + p][tx];
}

// ---------------------------------------------------------------------------
__global__ __launch_bounds__(256) void concat3_kernel(
    const float* __restrict__ a, const float* __restrict__ b,
    const float* __restrict__ c, float* __restrict__ o)
{
    int i = blockIdx.x * 256 + threadIdx.x;
    if (i < 512) { o[i] = a[i]; o[512 + i] = b[i]; o[1024 + i] = c[i]; }
}

// ---------------------------------------------------------------------------
// LayerNorm: f32 input rows of 512 -> bf16 output. One wave per row.
// ---------------------------------------------------------------------------
__global__ __launch_bounds__(256) void ln_kernel(
    const float* __restrict__ x,
    const float* __restrict__ g,
    const float* __restrict__ b,
    unsigned short* __restrict__ out, int rows)
{
    int row  = blockIdx.x * 4 + (threadIdx.x >> 6);
    int lane = threadIdx.x & 63;
    if (row >= rows) return;
    const float* xr = x + (size_t)row * 512 + lane * 8;
    float4 d0 = *(const float4*)xr;
    float4 d1 = *(const float4*)(xr + 4);
    float v[8] = {d0.x, d0.y, d0.z, d0.w, d1.x, d1.y, d1.z, d1.w};
    float s = 0.f, ss = 0.f;
#pragma unroll
    for (int j = 0; j < 8; ++j) { s += v[j]; ss += v[j] * v[j]; }
#pragma unroll
    for (int o = 32; o > 0; o >>= 1) { s += __shfl_xor(s, o); ss += __shfl_xor(ss, o); }
    float mu   = s * (1.0f / 512.0f);
    float var  = ss * (1.0f / 512.0f) - mu * mu;
    var = fmaxf(var, 0.0f);
    float rstd = rsqrtf(var + 1e-5f);
    float4 g0 = *(const float4*)(g + lane * 8);
    float4 g1 = *(const float4*)(g + lane * 8 + 4);
    float4 b0 = *(const float4*)(b + lane * 8);
    float4 b1 = *(const float4*)(b + lane * 8 + 4);
    float gg[8] = {g0.x, g0.y, g0.z, g0.w, g1.x, g1.y, g1.z, g1.w};
    float bb[8] = {b0.x, b0.y, b0.z, b0.w, b1.x, b1.y, b1.z, b1.w};
    uint4 res; unsigned short* rs = (unsigned short*)&res;
#pragma unroll
    for (int j = 0; j < 8; ++j)
        rs[j] = f2b((v[j] - mu) * rstd * gg[j] + bb[j]);
    *(uint4*)(out + (size_t)row * 512 + lane * 8) = res;
}

// ---------------------------------------------------------------------------
// 2-blocks/CU pipelined GEMM: C = act(A @ Bt^T + bias) [+res]
// BM=256 x BN=128 x BK=32; 512 threads = 8 waves (4M x 2N), per-wave 64x64
// output (acc[4][4] of 16x16x32 mfma). LDS = 3-buffer ring (lead 2 tiles):
// LA[3][256][32] + LB[3][128][32] = 72 KiB -> TWO blocks per CU, so one
// block's MFMA cluster fills the other's read/stage/barrier windows (the
// R5 profile showed 1 block/CU exposing ~55% idle per phase).
// Per K-tile (one phase): {ds_read 8 frags ; STG tile t+2 (3 gload_lds) ;
// s_waitcnt vmcnt(3) (counted — tile t+1's stages landed; NEVER 0 in loop) ;
// barrier ; setprio(1) 16 MFMA setprio(0) ; barrier}.
// Bank swizzle: 16B group ^= ((row>>1)&3) on stage SOURCE and read addr
// (involution, both-sides rule; measured 0 conflicts). XCD-chunked blockIdx
// swizzle (bijective when nwg%8==0; guarded) keeps A-panel sharers on one L2.
// ---------------------------------------------------------------------------
__global__ __launch_bounds__(512, 4) void gemm_bt_kernel(
    const unsigned short* __restrict__ A,    // [M,K] bf16
    const unsigned short* __restrict__ Bt,   // [N,K] bf16
    const float* __restrict__ bias,
    const float* __restrict__ residual,
    void* __restrict__ Cv,
    int M, int N, int K, int act_gelu, int out_f32)
{
    __shared__ unsigned short LA[3][256][32];   // 49152 B
    __shared__ unsigned short LB[3][128][32];   // 24576 B

    const int tid  = threadIdx.x;
    const int w    = tid >> 6, lane = tid & 63;
    const int quad = lane >> 4, l16 = lane & 15;
    const int wm   = (w >> 1) * 64, wn = (w & 1) * 64;   // 4M x 2N wave grid

    int bx = blockIdx.x, by = blockIdx.y;
    {
        int nwg = gridDim.x * gridDim.y;
        if ((nwg & 7) == 0) {
            int lid = by * gridDim.x + bx;
            int cpx = nwg >> 3;
            lid = (lid & 7) * cpx + (lid >> 3);
            bx = lid % gridDim.x;
            by = lid / gridDim.x;
        }
    }
    const int bm = by * 256, bn = bx * 128;

    // staging map: wave w covers rows w*16..w*16+15 (+128 for A's 2nd call);
    // lane -> (row = w*16 + (l>>2), grp = l&3); source k-group swizzled:
    // sg = (l&3) ^ ((row>>1)&3) = (l&3) ^ ((l>>3)&3)  (w*16, +128 are 0 mod 4).
    const int srow = w * 16 + (lane >> 2);
    const int sg   = (lane & 3) ^ ((lane >> 3) & 3);
    const unsigned short* a_src = A  + (size_t)(bm + srow) * K + sg * 8;
    const unsigned short* b_src = Bt + (size_t)(bn + srow) * K + sg * 8;
    const size_t a_skip = (size_t)128 * K;

    // fragment-read swizzle: row = 16*base + l16 -> (row>>1)&3 == (l16>>1)&3
    const int axor = (quad ^ ((l16 >> 1) & 3)) * 8;

    f32x4 acc[4][4] = {};
    const int nt = K >> 5;                  // 32-wide K-tiles: 16 or 64

    auto STG = [&](int sb, int kt) {
        const int ko = kt << 5;
        gload16(&LA[sb][w * 16][0],       a_src + ko);
        gload16(&LA[sb][128 + w * 16][0], a_src + a_skip + ko);
        gload16(&LB[sb][w * 16][0],       b_src + ko);
    };

    // prologue: stage tiles 0 and 1 (6 loads out); wait tile 0 (<=3 out)
    STG(0, 0);
    STG(1, 1);
    asm volatile("s_waitcnt vmcnt(3)" ::: "memory");
    __builtin_amdgcn_s_barrier();

    int cur = 0, stg = 2;
    for (int t = 0; t < nt; ++t) {
        s16x8 a4[4], b4[4];
#pragma unroll
        for (int m = 0; m < 4; ++m)
            a4[m] = *(const s16x8*)&LA[cur][wm + m * 16 + l16][axor];
#pragma unroll
        for (int n = 0; n < 4; ++n)
            b4[n] = *(const s16x8*)&LB[cur][wn + n * 16 + l16][axor];

        // stage tile t+2 into ring slot (tail: dummy k=0 into never-read slot)
        STG(stg, (t + 2 < nt) ? t + 2 : 0);
        // counted wait: tile t+1's 3 stages landed (t+2's 3 remain in flight)
        asm volatile("s_waitcnt vmcnt(3)" ::: "memory");
        __builtin_amdgcn_sched_barrier(0);
        __builtin_amdgcn_s_barrier();
        __builtin_amdgcn_sched_barrier(0);

        __builtin_amdgcn_s_setprio(1);
#pragma unroll
        for (int m = 0; m < 4; ++m)
#pragma unroll
            for (int n = 0; n < 4; ++n)
                acc[m][n] = __builtin_amdgcn_mfma_f32_16x16x32_bf16(a4[m], b4[n], acc[m][n], 0, 0, 0);
        __builtin_amdgcn_s_setprio(0);
        __builtin_amdgcn_sched_barrier(0);
        __builtin_amdgcn_s_barrier();

        cur = (cur == 2) ? 0 : cur + 1;
        stg = (stg == 2) ? 0 : stg + 1;
    }
    asm volatile("s_waitcnt vmcnt(0)" ::: "memory");   // drain dummy stages

#pragma unroll
    for (int m = 0; m < 4; ++m) {
#pragma unroll
        for (int n = 0; n < 4; ++n) {
#pragma unroll
            for (int r = 0; r < 4; ++r) {
                int row = bm + wm + m * 16 + quad * 4 + r;
                int col = bn + wn + n * 16 + l16;
                float val = acc[m][n][r] + bias[col];
                if (act_gelu) val = gelu_fast(val);
                if (residual) val += residual[(size_t)row * N + col];
                if (out_f32) ((float*)Cv)[(size_t)row * N + col] = val;
                else ((unsigned short*)Cv)[(size_t)row * N + col] = f2b(val);
            }
        }
    }
}

// ---------------------------------------------------------------------------
// Attention: one block per batch. qkv packed [T,1536] bf16 (q|k|v),
// x residual f32, x2 out f32. Ps/Vs LDS XOR-swizzled (conflict-free).
// ---------------------------------------------------------------------------
__global__ __launch_bounds__(256) void attn_kernel(
    const unsigned short* __restrict__ qkv,
    const float* __restrict__ x,
    float* __restrict__ x2)
{
    __shared__ unsigned short Ps[128][128];
    __shared__ unsigned short Vs[64][128];

    int b = blockIdx.x;
    int tid = threadIdx.x;
    int wave = tid >> 6, lane = tid & 63;
    int quad = lane >> 4, l16 = lane & 15;
    const unsigned short* qb = qkv + (size_t)b * 128 * 1536;
    const size_t bo = (size_t)b * 128 * 512;

    f32x4 acc[2][8] = {};
    for (int e0 = 0; e0 < 512; e0 += 32) {
        s16x8 a0 = *(const s16x8*)(qb + (size_t)(wave * 32 + l16) * 1536 + e0 + quad * 8);
        s16x8 a1 = *(const s16x8*)(qb + (size_t)(wave * 32 + 16 + l16) * 1536 + e0 + quad * 8);
#pragma unroll
        for (int j = 0; j < 8; ++j) {
            s16x8 bf = *(const s16x8*)(qb + (size_t)(j * 16 + l16) * 1536 + 512 + e0 + quad * 8);
            acc[0][j] = __builtin_amdgcn_mfma_f32_16x16x32_bf16(a0, bf, acc[0][j], 0, 0, 0);
            acc[1][j] = __builtin_amdgcn_mfma_f32_16x16x32_bf16(a1, bf, acc[1][j], 0, 0, 0);
        }
    }

    const float NEG = -1e30f;
#pragma unroll
    for (int i = 0; i < 2; ++i) {
#pragma unroll
        for (int r = 0; r < 4; ++r) {
            int t = wave * 32 + i * 16 + quad * 4 + r;
            float m = NEG;
#pragma unroll
            for (int j = 0; j < 8; ++j) {
                int s_col = j * 16 + l16;
                float val = acc[i][j][r] * 0.125f;
                val = (s_col <= t) ? val : NEG;
                acc[i][j][r] = val;
                m = fmaxf(m, val);
            }
            for (int o = 1; o < 16; o <<= 1) m = fmaxf(m, __shfl_xor(m, o));
            float sm = 0.f;
#pragma unroll
            for (int j = 0; j < 8; ++j) {
                float e = __expf(acc[i][j][r] - m);
                acc[i][j][r] = e;
                sm += e;
            }
            for (int o = 1; o < 16; o <<= 1) sm += __shfl_xor(sm, o);
            float inv = 1.0f / sm;
#pragma unroll
            for (int j = 0; j < 8; ++j) {
                int g = (j * 2 + (l16 >> 3)) ^ (t & 7);
                Ps[t][g * 8 + (l16 & 7)] = f2b(acc[i][j][r] * inv);
            }
        }
    }
    __syncthreads();

    const float* xb = x + bo;
    float* ob = x2 + bo;
    for (int e0 = 0; e0 < 512; e0 += 64) {
        if (e0) __syncthreads();
#pragma unroll
        for (int p = 0; p < 4; ++p) {
            int s = (tid >> 3) + p * 32;
            int c = (tid & 7) * 8;
            uint4 d = *(const uint4*)(qb + (size_t)s * 1536 + 1024 + e0 + c);
            const unsigned short* dsv = (const unsigned short*)&d;
#pragma unroll
            for (int j = 0; j < 8; ++j) {
                int rr = c + j;
                int g = (s >> 3) ^ j ^ (tid & 7);
                Vs[rr][g * 8 + (s & 7)] = dsv[j];
            }
        }
        __syncthreads();

        f32x4 acc2[2][4] = {};
#pragma unroll
        for (int ks = 0; ks < 4; ++ks) {
            int gp = ((ks * 4 + quad) ^ (l16 & 7)) * 8;
            s16x8 a0 = *(const s16x8*)(&Ps[wave * 32 + l16][gp]);
            s16x8 a1 = *(const s16x8*)(&Ps[wave * 32 + 16 + l16][gp]);
#pragma unroll
            for (int n = 0; n < 4; ++n) {
                int gv = ((ks * 4 + quad) ^ (l16 & 7) ^ ((2 * n + (l16 >> 3)) & 7)) * 8;
                s16x8 bf = *(const s16x8*)(&Vs[n * 16 + l16][gv]);
                acc2[0][n] = __builtin_amdgcn_mfma_f32_16x16x32_bf16(a0, bf, acc2[0][n], 0, 0, 0);
                acc2[1][n] = __builtin_amdgcn_mfma_f32_16x16x32_bf16(a1, bf, acc2[1][n], 0, 0, 0);
            }
        }
#pragma unroll
        for (int i = 0; i < 2; ++i) {
#pragma unroll
            for (int n = 0; n < 4; ++n) {
#pragma unroll
                for (int r = 0; r < 4; ++r) {
                    int t = wave * 32 + i * 16 + quad * 4 + r;
                    int e = e0 + n * 16 + l16;
                    ob[(size_t)t * 512 + e] = acc2[i][n][r] + xb[(size_t)t * 512 + e];
                }
            }
        }
    }
}

// ---------------------------------------------------------------------------
extern "C" void kernel_launch(void* const* d_in, const int* in_sizes, int n_in,
                              void* d_out, int out_size, void* d_ws, size_t ws_size,
                              hipStream_t stream) {
    const float* x   = (const float*)d_in[0];
    const float* wq  = (const float*)d_in[1];
    const float* bq  = (const float*)d_in[2];
    const float* wk  = (const float*)d_in[3];
    const float* bk  = (const float*)d_in[4];
    const float* wv  = (const float*)d_in[5];
    const float* bv  = (const float*)d_in[6];
    const float* g1  = (const float*)d_in[7];
    const float* b1  = (const float*)d_in[8];
    const float* g2  = (const float*)d_in[9];
    const float* b2  = (const float*)d_in[10];
    const float* w1  = (const float*)d_in[11];
    const float* bm1 = (const float*)d_in[12];
    const float* w2  = (const float*)d_in[13];
    const float* bm2 = (const float*)d_in[14];
    float* out = (float*)d_out;

    const int BATCH = 512, T = 128;
    dim3 blk(256), blkg(512);

    // ---- one-time weight convert+transpose f32[K,N] -> bf16[N,K] ----
    unsigned short* wqt = (unsigned short*)d_ws;
    unsigned short* wkt = wqt + 262144;
    unsigned short* wvt = wkt + 262144;
    unsigned short* w1t = wvt + 262144;   // [2048, 512]
    unsigned short* w2t = w1t + 1048576;  // [512, 2048]
    float* bqkv = (float*)(w2t + 1048576);
    cvt_t_kernel<<<dim3(16, 16), blk, 0, stream>>>(wq, wqt, 512, 512);
    cvt_t_kernel<<<dim3(16, 16), blk, 0, stream>>>(wk, wkt, 512, 512);
    cvt_t_kernel<<<dim3(16, 16), blk, 0, stream>>>(wv, wvt, 512, 512);
    cvt_t_kernel<<<dim3(64, 16), blk, 0, stream>>>(w1, w1t, 512, 2048);
    cvt_t_kernel<<<dim3(16, 64), blk, 0, stream>>>(w2, w2t, 2048, 512);
    concat3_kernel<<<dim3(2), blk, 0, stream>>>(bq, bk, bv, bqkv);

    // ---- dynamic region: chunk batch so it fits ws (C>=8 -> R%256==0) ----
    int C = 512;
    while (C > 8 && 5773312ull + (size_t)C * 917504ull > ws_size) C >>= 1;

    const int R = C * T;
    const size_t S = (size_t)R * 512;
    char* dyn = (char*)(bqkv + 1536);
    unsigned short* h   = (unsigned short*)dyn;
    float*          x2f = (float*)(dyn + S * 2);
    unsigned short* qkv = (unsigned short*)(dyn + S * 2 + S * 4);
    unsigned short* mff = qkv;

    for (int b0 = 0; b0 < BATCH; b0 += C) {
        const size_t off = (size_t)b0 * T * 512;
        // attention sub-block
        ln_kernel<<<R / 4, blk, 0, stream>>>(x + off, g1, b1, h, R);
        gemm_bt_kernel<<<dim3(12, R / 256), blkg, 0, stream>>>(h, wqt, bqkv, nullptr, qkv, R, 1536, 512, 0, 0);
        attn_kernel<<<C, blk, 0, stream>>>(qkv, x + off, x2f);
        // MLP sub-block
        ln_kernel<<<R / 4, blk, 0, stream>>>(x2f, g2, b2, h, R);
        gemm_bt_kernel<<<dim3(16, R / 256), blkg, 0, stream>>>(h, w1t, bm1, nullptr, mff, R, 2048, 512, 1, 0);
        gemm_bt_kernel<<<dim3(4, R / 256), blkg, 0, stream>>>(mff, w2t, bm2, x2f, out + off, R, 512, 2048, 0, 1);
    }
}